// Round 1
// baseline (114.326 us; speedup 1.0000x reference)
//
#include <hip/hip_runtime.h>
#include <cmath>

#define EMBED   1024
#define EPB     8
#define NB      64
#define KTOP    2

// ---------------------------------------------------------------------------
// Kernel 1: reciprocal L2 norms of the 512 expert-key rows.
// One wave per row; lane reads float4 strided so the wave is coalesced.
// ---------------------------------------------------------------------------
__global__ void key_rnorm_kernel(const float* __restrict__ ek,
                                 float* __restrict__ rnorm, int nrows) {
    int wave = (int)((blockIdx.x * blockDim.x + threadIdx.x) >> 6);
    int lane = threadIdx.x & 63;
    if (wave >= nrows) return;
    const float4* row = (const float4*)(ek + (size_t)wave * EMBED);
    float s = 0.f;
#pragma unroll
    for (int c = 0; c < 4; ++c) {
        float4 v = row[c * 64 + lane];
        s += v.x * v.x + v.y * v.y + v.z * v.z + v.w * v.w;
    }
#pragma unroll
    for (int off = 32; off; off >>= 1) s += __shfl_xor(s, off, 64);
    if (lane == 0) rnorm[wave] = 1.0f / fmaxf(sqrtf(s), 1e-12f);
}

// ---------------------------------------------------------------------------
// Kernel 2: one wave per token.
//   - lane loads 16 floats of h (4x float4, coalesced), keeps in registers
//   - loops 8 experts of the token's bucket, accumulating dots
//   - butterfly-reduce ||h||^2 + 8 dots across 64 lanes
//   - lane 0: softmax over 8, top-2 (lowest-index tie-break like jax top_k),
//     renormalize, write gid (as float) and w.
// ---------------------------------------------------------------------------
__global__ void router_kernel(const float* __restrict__ h,
                              const int*   __restrict__ op_id,
                              const float* __restrict__ ek,
                              const float* __restrict__ rk,
                              float* __restrict__ out_gid,
                              float* __restrict__ out_w,
                              int ntok) {
    int wave = (int)((blockIdx.x * blockDim.x + threadIdx.x) >> 6);
    int lane = threadIdx.x & 63;
    if (wave >= ntok) return;

    int b = op_id[wave];
    b = min(max(b, 0), NB - 1);

    const float4* hrow = (const float4*)(h + (size_t)wave * EMBED);
    float4 hv[4];
    float hh = 0.f;
#pragma unroll
    for (int c = 0; c < 4; ++c) {
        hv[c] = hrow[c * 64 + lane];
        hh += hv[c].x * hv[c].x + hv[c].y * hv[c].y +
              hv[c].z * hv[c].z + hv[c].w * hv[c].w;
    }

    const float4* kbase = (const float4*)(ek + (size_t)b * EPB * EMBED);
    float dot[EPB];
#pragma unroll
    for (int e = 0; e < EPB; ++e) {
        float d = 0.f;
#pragma unroll
        for (int c = 0; c < 4; ++c) {
            float4 kv = kbase[e * 256 + c * 64 + lane];
            d += hv[c].x * kv.x + hv[c].y * kv.y +
                 hv[c].z * kv.z + hv[c].w * kv.w;
        }
        dot[e] = d;
    }

    // 64-lane butterfly reduction of hh + dot[0..7]
#pragma unroll
    for (int off = 32; off; off >>= 1) {
        hh += __shfl_xor(hh, off, 64);
#pragma unroll
        for (int e = 0; e < EPB; ++e) dot[e] += __shfl_xor(dot[e], off, 64);
    }

    if (lane == 0) {
        float rh = 1.0f / fmaxf(sqrtf(hh), 1e-12f);
        float sc[EPB];
        float m = -1e30f;
#pragma unroll
        for (int e = 0; e < EPB; ++e) {
            sc[e] = dot[e] * rh * rk[b * EPB + e];   // TAU = 1.0 -> no scale
            m = fmaxf(m, sc[e]);
        }
        float ex[EPB];
        float Z = 0.f;
#pragma unroll
        for (int e = 0; e < EPB; ++e) { ex[e] = expf(sc[e] - m); Z += ex[e]; }

        // top-2 with lowest-index tie-break (strict > while scanning ascending)
        int i1 = 0;
#pragma unroll
        for (int e = 1; e < EPB; ++e) if (ex[e] > ex[i1]) i1 = e;
        int i2 = (i1 == 0) ? 1 : 0;
#pragma unroll
        for (int e = 0; e < EPB; ++e)
            if (e != i1 && ex[e] > ex[i2]) i2 = e;

        float p1 = ex[i1] / Z;
        float p2 = ex[i2] / Z;
        float wsum = p1 + p2 + 1e-9f;

        out_gid[(size_t)wave * KTOP + 0] = (float)(b * EPB + i1);
        out_gid[(size_t)wave * KTOP + 1] = (float)(b * EPB + i2);
        out_w  [(size_t)wave * KTOP + 0] = p1 / wsum;
        out_w  [(size_t)wave * KTOP + 1] = p2 / wsum;
    }
}

extern "C" void kernel_launch(void* const* d_in, const int* in_sizes, int n_in,
                              void* d_out, int out_size, void* d_ws, size_t ws_size,
                              hipStream_t stream) {
    const float* h     = (const float*)d_in[0];
    const int*   op_id = (const int*)  d_in[1];
    const float* ek    = (const float*)d_in[2];

    int ntok = in_sizes[1];            // B*T tokens
    int nrows = NB * EPB;              // 512 key rows

    float* rk      = (float*)d_ws;             // 512 floats of scratch
    float* out_gid = (float*)d_out;            // first output: gid as float
    float* out_w   = out_gid + (size_t)ntok * KTOP;  // second output: w

    // Kernel 1: 512 waves (4 waves / 256-thread block)
    int blocks1 = (nrows * 64 + 255) / 256;
    key_rnorm_kernel<<<blocks1, 256, 0, stream>>>(ek, rk, nrows);

    // Kernel 2: one wave per token
    int blocks2 = (ntok * 64 + 255) / 256;
    router_kernel<<<blocks2, 256, 0, stream>>>(h, op_id, ek, rk, out_gid, out_w, ntok);
}